// Round 2
// baseline (1875.851 us; speedup 1.0000x reference)
//
#include <hip/hip_runtime.h>
#include <hip/hip_bf16.h>
#include <math.h>

// Mamba single-step recurrence, BATCH=2048.
// D_MODEL=1024, D_STATE=16, D_CONV=4, D_INNER=2048, DT_RANK=64, IN=OUT=512.
//
// Pipeline:
//  K1: h   = x @ w_inp + b_inp            (2048x512)@(512x1024)
//  K2: xz  = h @ in_proj_w^T              (2048x1024)@(1024x4096)  [B stored N,K]
//  K3: conv shift+silu -> xc, write conv part of new rnn state
//  K4: xdb = xc @ x_proj_w^T              (2048x2048)@(2048x96)    [B stored N,K]
//  K5: dt = softplus(xdb[:, :64]@dt_proj_w^T + b); ssm update; y = (s@C + D*xc)*silu(z)
//  K6: core= y @ out_proj_w^T             (2048x2048)@(2048x1024)  [B stored N,K]
//  K7: out = core @ w_outp + b_outp       (2048x1024)@(1024x512)

#define BATCH 2048
#define D_INNER 2048
#define D_STATE 16
#define D_CONV 4
#define DT_RANK 64          // (1024+15)//16 == 64  (was wrongly 65 in round 1)
#define XDB_N 96            // DT_RANK + 2*D_STATE
#define RNN_ROW 40960       // D_INNER*(D_CONV+D_STATE)

__device__ __forceinline__ float silu_f(float v) {
    return v / (1.f + __expf(-v));
}

// ---------------------------------------------------------------------------
// Tiled fp32 GEMM: C[M,N] = A[M,K] @ B + bias.
// BT=false: B stored row-major [K,N].  BT=true: B stored row-major [N,K] (B^T).
// 128x128 tile, BK=8, 256 threads, 8x8 per thread (split 4+4 columns, 64 apart).
// M,N multiples of 128; K multiple of 8.
// ---------------------------------------------------------------------------
template<bool BT, bool BIAS>
__global__ __launch_bounds__(256, 2)
void gemm128(const float* __restrict__ A, const float* __restrict__ B,
             const float* __restrict__ bias, float* __restrict__ C,
             int M, int N, int K) {
    __shared__ float As[8][132];
    __shared__ float Bs[8][132];
    const int tid = threadIdx.x;
    const int tx = tid & 15;   // 0..15 -> column groups
    const int ty = tid >> 4;   // 0..15 -> row groups
    const int m0 = blockIdx.y * 128;
    const int n0 = blockIdx.x * 128;

    float acc[8][8];
#pragma unroll
    for (int i = 0; i < 8; ++i)
#pragma unroll
        for (int j = 0; j < 8; ++j) acc[i][j] = 0.f;

    const int am = tid >> 1;         // 0..127 row of tile
    const int ak = (tid & 1) * 4;    // 0 or 4
    const int bkn = tid >> 5;        // 0..7 (normal layout k row)
    const int bnn = (tid & 31) * 4;  // 0..124 (normal layout n col)

    for (int k0 = 0; k0 < K; k0 += 8) {
        {
            float4 a4 = *(const float4*)&A[(size_t)(m0 + am) * K + k0 + ak];
            As[ak + 0][am] = a4.x; As[ak + 1][am] = a4.y;
            As[ak + 2][am] = a4.z; As[ak + 3][am] = a4.w;
        }
        if (!BT) {
            float4 b4 = *(const float4*)&B[(size_t)(k0 + bkn) * N + n0 + bnn];
            *(float4*)&Bs[bkn][bnn] = b4;
        } else {
            float4 b4 = *(const float4*)&B[(size_t)(n0 + am) * K + k0 + ak];
            Bs[ak + 0][am] = b4.x; Bs[ak + 1][am] = b4.y;
            Bs[ak + 2][am] = b4.z; Bs[ak + 3][am] = b4.w;
        }
        __syncthreads();
#pragma unroll
        for (int kk = 0; kk < 8; ++kk) {
            float a[8], b[8];
            *(float4*)&a[0] = *(const float4*)&As[kk][ty * 8];
            *(float4*)&a[4] = *(const float4*)&As[kk][ty * 8 + 4];
            *(float4*)&b[0] = *(const float4*)&Bs[kk][tx * 4];          // cols n0+tx*4+j
            *(float4*)&b[4] = *(const float4*)&Bs[kk][64 + tx * 4];     // cols n0+64+tx*4+j
#pragma unroll
            for (int i = 0; i < 8; ++i)
#pragma unroll
                for (int j = 0; j < 8; ++j)
                    acc[i][j] = fmaf(a[i], b[j], acc[i][j]);
        }
        __syncthreads();
    }

    const int nA = n0 + tx * 4;
    const int nB = n0 + 64 + tx * 4;
#pragma unroll
    for (int i = 0; i < 8; ++i) {
        const int m = m0 + ty * 8 + i;
        float4 v0 = make_float4(acc[i][0], acc[i][1], acc[i][2], acc[i][3]);
        float4 v1 = make_float4(acc[i][4], acc[i][5], acc[i][6], acc[i][7]);
        if (BIAS) {
            v0.x += bias[nA]; v0.y += bias[nA + 1]; v0.z += bias[nA + 2]; v0.w += bias[nA + 3];
            v1.x += bias[nB]; v1.y += bias[nB + 1]; v1.z += bias[nB + 2]; v1.w += bias[nB + 3];
        }
        *(float4*)&C[(size_t)m * N + nA] = v0;
        *(float4*)&C[(size_t)m * N + nB] = v1;
    }
}

// ---------------------------------------------------------------------------
// K3: conv state shift + depthwise conv + silu. One thread per (b,d).
// ---------------------------------------------------------------------------
__global__ __launch_bounds__(256)
void conv_kernel(const float* __restrict__ rnn_in, const float* __restrict__ xz,
                 const float* __restrict__ conv_w, const float* __restrict__ conv_b,
                 float* __restrict__ xc, float* __restrict__ rnn_out) {
    const int idx = blockIdx.x * 256 + threadIdx.x;   // b*2048 + d
    const int b = idx >> 11;
    const int d = idx & 2047;
    const size_t off = (size_t)b * RNN_ROW + (size_t)d * 20;
    float4 cs = *(const float4*)&rnn_in[off];
    const float xi = xz[(size_t)b * 4096 + d];
    float4 w = *(const float4*)&conv_w[d * 4];
    float pre = cs.y * w.x + cs.z * w.y + cs.w * w.z + xi * w.w + conv_b[d];
    xc[idx] = silu_f(pre);
    float4 ns = make_float4(cs.y, cs.z, cs.w, xi);
    *(float4*)&rnn_out[off] = ns;
}

// ---------------------------------------------------------------------------
// K4: xdb[b][n] = sum_k xc[b][k]*x_proj_w[n][k], n<96.
// 256 blocks, each handles 8 batch rows over full K=2048 (chunks of 256 in LDS).
// Thread (r=tid/32, lane=tid%32) accumulates n = lane, lane+32, lane+64.
// x_proj_w rows stream through L1/L2 (768 KB total, fully cached).
// ---------------------------------------------------------------------------
__global__ __launch_bounds__(256)
void xproj_kernel(const float* __restrict__ xc, const float* __restrict__ xw,
                  float* __restrict__ xdb) {
    __shared__ float xs[8][256];
    const int tid = threadIdx.x;
    const int b0 = blockIdx.x * 8;
    const int r = tid >> 5;
    const int lane = tid & 31;
    float acc0 = 0.f, acc1 = 0.f, acc2 = 0.f;
    for (int k0 = 0; k0 < 2048; k0 += 256) {
        __syncthreads();
        for (int l = tid; l < 8 * 256; l += 256) {
            int row = l >> 8, c = l & 255;
            xs[row][c] = xc[(size_t)(b0 + row) * 2048 + k0 + c];
        }
        __syncthreads();
#pragma unroll 4
        for (int k = 0; k < 256; k += 4) {
            float4 xv = *(const float4*)&xs[r][k];
            float4 w0 = *(const float4*)&xw[(size_t)lane * 2048 + k0 + k];
            float4 w1 = *(const float4*)&xw[(size_t)(lane + 32) * 2048 + k0 + k];
            float4 w2 = *(const float4*)&xw[(size_t)(lane + 64) * 2048 + k0 + k];
            acc0 = fmaf(xv.x, w0.x, fmaf(xv.y, w0.y, fmaf(xv.z, w0.z, fmaf(xv.w, w0.w, acc0))));
            acc1 = fmaf(xv.x, w1.x, fmaf(xv.y, w1.y, fmaf(xv.z, w1.z, fmaf(xv.w, w1.w, acc1))));
            acc2 = fmaf(xv.x, w2.x, fmaf(xv.y, w2.y, fmaf(xv.z, w2.z, fmaf(xv.w, w2.w, acc2))));
        }
    }
    xdb[(size_t)(b0 + r) * XDB_N + lane] = acc0;
    xdb[(size_t)(b0 + r) * XDB_N + lane + 32] = acc1;
    xdb[(size_t)(b0 + r) * XDB_N + lane + 64] = acc2;
}

// ---------------------------------------------------------------------------
// K5: fused dt GEMM (K=64) + softplus + SSM state update + y = (s.C + D*xc)*silu(z).
// Grid (16 d-tiles x 64 b-tiles), 128 threads (one d each), 32 b per block.
// dt_proj_w tile staged in LDS, row stride 65 (odd) so the per-thread row
// reads hit distinct banks (stride-64 would put all lanes on one bank).
// ---------------------------------------------------------------------------
__global__ __launch_bounds__(128)
void ssm_kernel(const float* __restrict__ rnn_in, const float* __restrict__ xdb,
                const float* __restrict__ xc, const float* __restrict__ xz,
                const float* __restrict__ dt_w, const float* __restrict__ dt_b,
                const float* __restrict__ A_log, const float* __restrict__ Dp,
                float* __restrict__ y, float* __restrict__ rnn_out) {
    __shared__ float dtw_s[128][65];
    __shared__ float xdb_s[XDB_N];
    const int tid = threadIdx.x;
    const int d0 = blockIdx.x * 128;
    const int b0 = blockIdx.y * 32;
    const int d = d0 + tid;

    for (int l = tid; l < 128 * DT_RANK; l += 128) {
        int dd = l >> 6, r = l & 63;
        dtw_s[dd][r] = dt_w[(size_t)(d0 + dd) * DT_RANK + r];
    }
    float A_row[16];
#pragma unroll
    for (int s = 0; s < 16; ++s) A_row[s] = -__expf(A_log[(size_t)d * 16 + s]);
    const float D_d = Dp[d];
    const float dtb_d = dt_b[d];
    __syncthreads();

    for (int bi = 0; bi < 32; ++bi) {
        const int b = b0 + bi;
        if (tid < XDB_N) xdb_s[tid] = xdb[(size_t)b * XDB_N + tid];
        __syncthreads();

        float acc = dtb_d;
#pragma unroll
        for (int r = 0; r < DT_RANK; ++r) acc = fmaf(xdb_s[r], dtw_s[tid][r], acc);
        const float dt = (acc > 20.f) ? acc : log1pf(__expf(acc));
        const float xc_v = xc[(size_t)b * 2048 + d];
        const float z_v = xz[(size_t)b * 4096 + 2048 + d];
        const float dtxc = dt * xc_v;

        const size_t soff = (size_t)b * RNN_ROW + (size_t)d * 20 + 4;
        float st[16];
        *(float4*)&st[0]  = *(const float4*)&rnn_in[soff + 0];
        *(float4*)&st[4]  = *(const float4*)&rnn_in[soff + 4];
        *(float4*)&st[8]  = *(const float4*)&rnn_in[soff + 8];
        *(float4*)&st[12] = *(const float4*)&rnn_in[soff + 12];

        float y_acc = D_d * xc_v;
#pragma unroll
        for (int s = 0; s < 16; ++s) {
            float Bv = xdb_s[DT_RANK + s];          // xdb[:, 64:80]
            float Cv = xdb_s[DT_RANK + 16 + s];     // xdb[:, 80:96]
            float ns = fmaf(st[s], __expf(dt * A_row[s]), dtxc * Bv);
            st[s] = ns;
            y_acc = fmaf(ns, Cv, y_acc);
        }
        *(float4*)&rnn_out[soff + 0]  = *(const float4*)&st[0];
        *(float4*)&rnn_out[soff + 4]  = *(const float4*)&st[4];
        *(float4*)&rnn_out[soff + 8]  = *(const float4*)&st[8];
        *(float4*)&rnn_out[soff + 12] = *(const float4*)&st[12];

        y[(size_t)b * 2048 + d] = y_acc * silu_f(z_v);
        __syncthreads();
    }
}

// ---------------------------------------------------------------------------
extern "C" void kernel_launch(void* const* d_in, const int* in_sizes, int n_in,
                              void* d_out, int out_size, void* d_ws, size_t ws_size,
                              hipStream_t stream) {
    const float* x         = (const float*)d_in[0];
    const float* rnn_in    = (const float*)d_in[1];
    const float* w_inp     = (const float*)d_in[2];
    const float* b_inp     = (const float*)d_in[3];
    const float* w_outp    = (const float*)d_in[4];
    const float* b_outp    = (const float*)d_in[5];
    const float* in_proj_w = (const float*)d_in[6];
    const float* conv_w    = (const float*)d_in[7];
    const float* conv_b    = (const float*)d_in[8];
    const float* x_proj_w  = (const float*)d_in[9];
    const float* dt_w      = (const float*)d_in[10];
    const float* dt_b      = (const float*)d_in[11];
    const float* A_log     = (const float*)d_in[12];
    const float* Dp        = (const float*)d_in[13];
    const float* out_proj_w= (const float*)d_in[14];

    float* out_main = (float*)d_out;                       // 2048*512
    float* rnn_out  = (float*)d_out + (size_t)BATCH * 512; // 2048*40960

    float* ws  = (float*)d_ws;
    float* h    = ws;                  // 2048*1024 = 2,097,152
    float* xz   = ws + 2097152;        // 2048*4096 = 8,388,608
    float* xc   = ws + 10485760;       // 2048*2048 = 4,194,304
    float* y    = ws + 14680064;       // 2048*2048 = 4,194,304
    float* xdb  = ws + 18874368;       // 2048*96   =   196,608
    float* core = ws;                  // alias h (dead after K2); 2048*1024

    // K1: h = x @ w_inp + b_inp
    gemm128<false, true><<<dim3(1024 / 128, BATCH / 128), 256, 0, stream>>>(
        x, w_inp, b_inp, h, BATCH, 1024, 512);
    // K2: xz = h @ in_proj_w^T
    gemm128<true, false><<<dim3(4096 / 128, BATCH / 128), 256, 0, stream>>>(
        h, in_proj_w, nullptr, xz, BATCH, 4096, 1024);
    // K3: conv
    conv_kernel<<<(BATCH * D_INNER) / 256, 256, 0, stream>>>(
        rnn_in, xz, conv_w, conv_b, xc, rnn_out);
    // K4: xdb = xc @ x_proj_w^T
    xproj_kernel<<<BATCH / 8, 256, 0, stream>>>(xc, x_proj_w, xdb);
    // K5: ssm
    ssm_kernel<<<dim3(D_INNER / 128, BATCH / 32), 128, 0, stream>>>(
        rnn_in, xdb, xc, xz, dt_w, dt_b, A_log, Dp, y, rnn_out);
    // K6: core = y @ out_proj_w^T
    gemm128<true, false><<<dim3(1024 / 128, BATCH / 128), 256, 0, stream>>>(
        y, out_proj_w, nullptr, core, BATCH, 1024, 2048);
    // K7: out = core @ w_outp + b_outp
    gemm128<false, true><<<dim3(512 / 128, BATCH / 128), 256, 0, stream>>>(
        core, w_outp, b_outp, out_main, BATCH, 512, 1024);
}